// Round 1
// baseline (179.032 us; speedup 1.0000x reference)
//
#include <hip/hip_runtime.h>
#include <cstdint>
#include <cstddef>

// Problem constants (B=2, N=M=8192, points are 3-float).
#define B_ 2
#define N_ 8192
#define M_ 8192
#define SPLITS 16
#define CHUNK (N_ / SPLITS)   // 512 points per block's inner loop

// ---------------------------------------------------------------------------
// Pass 1: for each (b, m) over ref points, min+argmin over all predicted
// points n. Split-N across blockIdx.y; combine splits with packed u64
// atomicMin: (float_bits(d2) << 32) | n_index. d2 >= 0 so uint ordering of
// the float bits == numeric ordering; ties pick the smallest n (matches
// jnp.argmin first-occurrence semantics).
// ---------------------------------------------------------------------------
__global__ __launch_bounds__(256) void k_min_over_pred(
    const float* __restrict__ pred_pts,   // [B, N, 3]
    const float* __restrict__ ref_pts,    // [B, M, 3]
    unsigned long long* __restrict__ packed)  // [B*M], init 0xFF..FF
{
    __shared__ float4 sp[CHUNK];
    const int t  = threadIdx.x;
    const int mb = blockIdx.x;   // m-block
    const int ns = blockIdx.y;   // n-split
    const int b  = blockIdx.z;
    const int m  = mb * 256 + t;

    // Stage this split's predicted-point chunk into LDS (2 points/thread).
    {
        const int p0 = 2 * t;
        const size_t gbase = ((size_t)b * N_ + (size_t)ns * CHUNK + p0) * 3;
        const float2* g = reinterpret_cast<const float2*>(pred_pts + gbase);
        float2 a0 = g[0], a1 = g[1], a2 = g[2];
        sp[p0]     = make_float4(a0.x, a0.y, a1.x, 0.f);
        sp[p0 + 1] = make_float4(a1.y, a2.x, a2.y, 0.f);
    }
    __syncthreads();

    const size_t rb = ((size_t)b * M_ + m) * 3;
    const float rx = ref_pts[rb], ry = ref_pts[rb + 1], rz = ref_pts[rb + 2];

    float best = 3.4e38f;
    int bidx = 0;
    #pragma unroll 8
    for (int j = 0; j < CHUNK; ++j) {
        float4 p = sp[j];             // broadcast ds_read_b128 (all lanes same addr)
        float dx = rx - p.x, dy = ry - p.y, dz = rz - p.z;
        float d2 = dx * dx + dy * dy + dz * dz;
        bool lt = d2 < best;          // strict < keeps first occurrence
        best = lt ? d2 : best;
        bidx = lt ? j : bidx;
    }

    unsigned long long pk =
        ((unsigned long long)__float_as_uint(best) << 32)
        | (unsigned)(ns * CHUNK + bidx);
    atomicMin(&packed[(size_t)b * M_ + m], pk);
}

// ---------------------------------------------------------------------------
// Pass 2: for each (b, n) over predicted points, min over all ref points m.
// Only the min value is needed (cham_xy). 32-bit atomicMin on float bits.
// ---------------------------------------------------------------------------
__global__ __launch_bounds__(256) void k_min_over_ref(
    const float* __restrict__ pred_pts,   // [B, N, 3]
    const float* __restrict__ ref_pts,    // [B, M, 3]
    unsigned int* __restrict__ colmin)    // [B*N], init 0xFFFFFFFF
{
    __shared__ float4 sp[CHUNK];
    const int t  = threadIdx.x;
    const int nb = blockIdx.x;   // n-block
    const int ms = blockIdx.y;   // m-split
    const int b  = blockIdx.z;
    const int n  = nb * 256 + t;

    {
        const int p0 = 2 * t;
        const size_t gbase = ((size_t)b * M_ + (size_t)ms * CHUNK + p0) * 3;
        const float2* g = reinterpret_cast<const float2*>(ref_pts + gbase);
        float2 a0 = g[0], a1 = g[1], a2 = g[2];
        sp[p0]     = make_float4(a0.x, a0.y, a1.x, 0.f);
        sp[p0 + 1] = make_float4(a1.y, a2.x, a2.y, 0.f);
    }
    __syncthreads();

    const size_t pb = ((size_t)b * N_ + n) * 3;
    const float px = pred_pts[pb], py = pred_pts[pb + 1], pz = pred_pts[pb + 2];

    float best = 3.4e38f;
    #pragma unroll 8
    for (int j = 0; j < CHUNK; ++j) {
        float4 p = sp[j];
        float dx = px - p.x, dy = py - p.y, dz = pz - p.z;
        float d2 = dx * dx + dy * dy + dz * dz;
        best = fminf(best, d2);
    }
    atomicMin(&colmin[(size_t)b * N_ + n], __float_as_uint(best));
}

// ---------------------------------------------------------------------------
// Pass 3: gather sdf/color at argmin, accumulate all four sums.
// Note reference semantics: closest[b,m] gathers REF sdfs/colors, compared
// against predicted sdfs/colors at position m (valid since N == M).
// ---------------------------------------------------------------------------
__global__ __launch_bounds__(256) void k_reduce(
    const unsigned long long* __restrict__ packed,  // [B*M]
    const unsigned int* __restrict__ colmin,        // [B*N]
    const float* __restrict__ pred_sdfs,            // [B*N]
    const float* __restrict__ pred_cols,            // [B*N*3]
    const float* __restrict__ ref_sdfs,             // [B*M]
    const float* __restrict__ ref_cols,             // [B*M*3]
    float* __restrict__ acc)  // [4]: sdf_sum, color_sum, chamyx_sum, chamxy_sum
{
    const int i = blockIdx.x * 256 + threadIdx.x;   // 0 .. B*M-1 (== B*N-1)
    const int b = i / M_;

    unsigned long long pk = packed[i];
    float minv = __uint_as_float((unsigned)(pk >> 32));
    int arg = (int)(unsigned)(pk & 0xFFFFFFFFull);

    float sdf = fabsf(ref_sdfs[(size_t)b * M_ + arg] - pred_sdfs[i]);
    const float* rc = ref_cols + ((size_t)b * M_ + arg) * 3;
    const float* pc = pred_cols + (size_t)i * 3;
    float col = fabsf(rc[0] - pc[0]) + fabsf(rc[1] - pc[1]) + fabsf(rc[2] - pc[2]);
    float chyx = minv;
    float chxy = __uint_as_float(colmin[i]);

    // wave-64 shuffle reduction
    #pragma unroll
    for (int off = 32; off > 0; off >>= 1) {
        sdf  += __shfl_down(sdf, off);
        col  += __shfl_down(col, off);
        chyx += __shfl_down(chyx, off);
        chxy += __shfl_down(chxy, off);
    }
    if ((threadIdx.x & 63) == 0) {
        atomicAdd(&acc[0], sdf);
        atomicAdd(&acc[1], col);
        atomicAdd(&acc[2], chyx);
        atomicAdd(&acc[3], chxy);
    }
}

__global__ void k_final(const float* __restrict__ acc, float* __restrict__ out)
{
    if (threadIdx.x == 0) {
        out[0] = acc[0] / (float)(B_ * M_);
        out[1] = acc[1] / (float)(B_ * M_ * 3);
        out[2] = acc[3] / (float)(B_ * N_) + acc[2] / (float)(B_ * M_);
    }
}

extern "C" void kernel_launch(void* const* d_in, const int* in_sizes, int n_in,
                              void* d_out, int out_size, void* d_ws, size_t ws_size,
                              hipStream_t stream) {
    const float* pred_pts  = (const float*)d_in[0];  // [B,N,3]
    const float* pred_sdfs = (const float*)d_in[1];  // [B,N,1]
    const float* pred_cols = (const float*)d_in[2];  // [B,N,3]
    const float* ref_pts   = (const float*)d_in[3];  // [B,M,3]
    const float* ref_sdfs  = (const float*)d_in[4];  // [B,M,1]
    const float* ref_cols  = (const float*)d_in[5];  // [B,M,3]
    float* out = (float*)d_out;

    // Workspace layout: [packed u64: B*M][colmin u32: B*N][acc float4]
    char* ws = (char*)d_ws;
    unsigned long long* packed = (unsigned long long*)ws;                 // 131072 B
    unsigned int* colmin = (unsigned int*)(ws + (size_t)B_ * M_ * 8);     // 65536 B
    float* acc = (float*)(ws + (size_t)B_ * M_ * 8 + (size_t)B_ * N_ * 4);

    hipMemsetAsync(ws, 0xFF, (size_t)B_ * M_ * 8 + (size_t)B_ * N_ * 4, stream);
    hipMemsetAsync(acc, 0, 4 * sizeof(float), stream);

    dim3 g1(M_ / 256, SPLITS, B_);
    k_min_over_pred<<<g1, 256, 0, stream>>>(pred_pts, ref_pts, packed);

    dim3 g2(N_ / 256, SPLITS, B_);
    k_min_over_ref<<<g2, 256, 0, stream>>>(pred_pts, ref_pts, colmin);

    k_reduce<<<(B_ * M_) / 256, 256, 0, stream>>>(
        packed, colmin, pred_sdfs, pred_cols, ref_sdfs, ref_cols, acc);

    k_final<<<1, 64, 0, stream>>>(acc, out);
}

// Round 2
// 131.019 us; speedup vs baseline: 1.3665x; 1.3665x over previous
//
#include <hip/hip_runtime.h>
#include <cstdint>
#include <cstddef>

// Problem constants (B=2, N=M=8192, points are 3 floats).
#define B_ 2
#define N_ 8192
#define M_ 8192
#define SPLITS 32
#define CHUNK (N_ / SPLITS)   // 256 staged points per block
#define RPT 4                 // register-blocked points per thread
#define TM (256 * RPT)        // 1024 "outer" points per block

// ---------------------------------------------------------------------------
// Fused pairwise-min kernel. grid = (M_/TM, 2*SPLITS, B).
//   role 0 (ns < SPLITS):  outer = ref points m (4/thread in regs),
//                          inner = predicted chunk from LDS;
//                          tracks min+argmin over n  -> packed_split u64.
//   role 1 (ns >= SPLITS): outer = predicted points n, inner = ref chunk;
//                          tracks min over m          -> colmin_split u32.
// Broadcast ds_read_b128 (all lanes read sp[j]) is conflict-free; R=4
// register blocking amortizes it over 36 VALU ops.
// Split results are plain stores (deterministic), reduced in k_reduce.
// ---------------------------------------------------------------------------
__global__ __launch_bounds__(256) void k_pairs(
    const float* __restrict__ pred_pts,            // [B, N, 3]
    const float* __restrict__ ref_pts,             // [B, M, 3]
    unsigned long long* __restrict__ packed_split, // [B][SPLITS][M]
    unsigned int* __restrict__ colmin_split)       // [B][SPLITS][N]
{
    __shared__ float4 sp[CHUNK];
    const int t  = threadIdx.x;
    const int ob = blockIdx.x;            // outer-point block
    const int sy = blockIdx.y;
    const int b  = blockIdx.z;
    const bool role_col = sy >= SPLITS;   // block-uniform branch
    const int ns = role_col ? sy - SPLITS : sy;

    const float* inner_pts = role_col ? ref_pts  : pred_pts;
    const float* outer_pts = role_col ? pred_pts : ref_pts;

    // Stage this split's inner chunk into LDS (1 point/thread, CHUNK==256).
    {
        const float* g = inner_pts + ((size_t)b * N_ + (size_t)ns * CHUNK + t) * 3;
        sp[t] = make_float4(g[0], g[1], g[2], 0.f);
    }
    __syncthreads();

    const int o0 = ob * TM + t;           // outer index for r=0 (stride 256 per r)
    float ox[RPT], oy[RPT], oz[RPT], best[RPT];
    int bidx[RPT];
    #pragma unroll
    for (int r = 0; r < RPT; ++r) {
        const float* g = outer_pts + ((size_t)b * M_ + o0 + r * 256) * 3;
        ox[r] = g[0]; oy[r] = g[1]; oz[r] = g[2];
        best[r] = 3.4e38f; bidx[r] = 0;
    }

    if (!role_col) {
        // min + argmin over inner (predicted) index
        #pragma unroll 4
        for (int j = 0; j < CHUNK; ++j) {
            float4 p = sp[j];
            #pragma unroll
            for (int r = 0; r < RPT; ++r) {
                float dx = ox[r] - p.x, dy = oy[r] - p.y, dz = oz[r] - p.z;
                float d2 = dx * dx + dy * dy + dz * dz;
                bool lt = d2 < best[r];          // strict < = first occurrence
                best[r] = lt ? d2 : best[r];
                bidx[r] = lt ? j : bidx[r];
            }
        }
        unsigned long long* dst = packed_split + (size_t)(b * SPLITS + ns) * M_;
        #pragma unroll
        for (int r = 0; r < RPT; ++r) {
            dst[o0 + r * 256] =
                ((unsigned long long)__float_as_uint(best[r]) << 32)
                | (unsigned)(ns * CHUNK + bidx[r]);
        }
    } else {
        // min only
        #pragma unroll 4
        for (int j = 0; j < CHUNK; ++j) {
            float4 p = sp[j];
            #pragma unroll
            for (int r = 0; r < RPT; ++r) {
                float dx = ox[r] - p.x, dy = oy[r] - p.y, dz = oz[r] - p.z;
                float d2 = dx * dx + dy * dy + dz * dz;
                best[r] = fminf(best[r], d2);
            }
        }
        unsigned int* dst = colmin_split + (size_t)(b * SPLITS + ns) * N_;
        #pragma unroll
        for (int r = 0; r < RPT; ++r)
            dst[o0 + r * 256] = __float_as_uint(best[r]);
    }
}

// ---------------------------------------------------------------------------
// Combine splits, gather sdf/color at argmin, accumulate the four sums.
// ---------------------------------------------------------------------------
__global__ __launch_bounds__(256) void k_reduce(
    const unsigned long long* __restrict__ packed_split, // [B][SPLITS][M]
    const unsigned int* __restrict__ colmin_split,       // [B][SPLITS][N]
    const float* __restrict__ pred_sdfs,                 // [B*N]
    const float* __restrict__ pred_cols,                 // [B*N*3]
    const float* __restrict__ ref_sdfs,                  // [B*M]
    const float* __restrict__ ref_cols,                  // [B*M*3]
    float* __restrict__ acc)  // [4]: sdf_sum, color_sum, chamyx_sum, chamxy_sum
{
    const int i = blockIdx.x * 256 + threadIdx.x;   // 0 .. B*M-1
    const int b = i / M_;
    const int m = i - b * M_;

    // u64 min across splits: value in high bits, inner index in low bits
    // (ties -> smallest global index = jnp first-occurrence).
    unsigned long long pk = 0xFFFFFFFFFFFFFFFFull;
    #pragma unroll 8
    for (int s = 0; s < SPLITS; ++s) {
        unsigned long long v = packed_split[(size_t)(b * SPLITS + s) * M_ + m];
        pk = v < pk ? v : pk;
    }
    unsigned int cm = 0xFFFFFFFFu;
    #pragma unroll 8
    for (int s = 0; s < SPLITS; ++s) {
        unsigned int v = colmin_split[(size_t)(b * SPLITS + s) * N_ + m];
        cm = v < cm ? v : cm;
    }

    float minv = __uint_as_float((unsigned)(pk >> 32));
    int arg = (int)(unsigned)(pk & 0xFFFFFFFFull);

    float sdf = fabsf(ref_sdfs[(size_t)b * M_ + arg] - pred_sdfs[i]);
    const float* rc = ref_cols + ((size_t)b * M_ + arg) * 3;
    const float* pc = pred_cols + (size_t)i * 3;
    float col = fabsf(rc[0] - pc[0]) + fabsf(rc[1] - pc[1]) + fabsf(rc[2] - pc[2]);
    float chyx = minv;
    float chxy = __uint_as_float(cm);

    #pragma unroll
    for (int off = 32; off > 0; off >>= 1) {
        sdf  += __shfl_down(sdf, off);
        col  += __shfl_down(col, off);
        chyx += __shfl_down(chyx, off);
        chxy += __shfl_down(chxy, off);
    }
    if ((threadIdx.x & 63) == 0) {
        atomicAdd(&acc[0], sdf);
        atomicAdd(&acc[1], col);
        atomicAdd(&acc[2], chyx);
        atomicAdd(&acc[3], chxy);
    }
}

__global__ void k_final(const float* __restrict__ acc, float* __restrict__ out)
{
    if (threadIdx.x == 0) {
        out[0] = acc[0] / (float)(B_ * M_);
        out[1] = acc[1] / (float)(B_ * M_ * 3);
        out[2] = acc[3] / (float)(B_ * N_) + acc[2] / (float)(B_ * M_);
    }
}

extern "C" void kernel_launch(void* const* d_in, const int* in_sizes, int n_in,
                              void* d_out, int out_size, void* d_ws, size_t ws_size,
                              hipStream_t stream) {
    const float* pred_pts  = (const float*)d_in[0];  // [B,N,3]
    const float* pred_sdfs = (const float*)d_in[1];  // [B,N,1]
    const float* pred_cols = (const float*)d_in[2];  // [B,N,3]
    const float* ref_pts   = (const float*)d_in[3];  // [B,M,3]
    const float* ref_sdfs  = (const float*)d_in[4];  // [B,M,1]
    const float* ref_cols  = (const float*)d_in[5];  // [B,M,3]
    float* out = (float*)d_out;

    // Workspace: [packed_split u64 B*SPLITS*M][colmin_split u32 B*SPLITS*N][acc f32 x4]
    char* ws = (char*)d_ws;
    unsigned long long* packed_split = (unsigned long long*)ws;                // 4 MiB
    unsigned int* colmin_split =
        (unsigned int*)(ws + (size_t)B_ * SPLITS * M_ * 8);                    // 2 MiB
    float* acc = (float*)(ws + (size_t)B_ * SPLITS * M_ * 8
                             + (size_t)B_ * SPLITS * N_ * 4);

    hipMemsetAsync(acc, 0, 4 * sizeof(float), stream);

    dim3 g1(M_ / TM, 2 * SPLITS, B_);   // (8, 64, 2) = 1024 blocks
    k_pairs<<<g1, 256, 0, stream>>>(pred_pts, ref_pts, packed_split, colmin_split);

    k_reduce<<<(B_ * M_) / 256, 256, 0, stream>>>(
        packed_split, colmin_split, pred_sdfs, pred_cols, ref_sdfs, ref_cols, acc);

    k_final<<<1, 64, 0, stream>>>(acc, out);
}

// Round 3
// 104.496 us; speedup vs baseline: 1.7133x; 1.2538x over previous
//
#include <hip/hip_runtime.h>
#include <cstdint>
#include <cstddef>

// B=2, N=M=8192, 3-float points.
#define B_ 2
#define N_ 8192
#define M_ 8192
#define COLSPLIT 4
#define CCHUNK (N_ / COLSPLIT)      // 2048 cols per block
#define NTILES (CCHUNK / 32)        // 64 col tiles of 32
#define ROWS_PER_WAVE 32
#define ROWS_PER_BLOCK 128          // 4 waves

typedef __attribute__((ext_vector_type(8))) short short8;
typedef __attribute__((ext_vector_type(16))) float f32x16;

union FragU { uint4 u; short8 s; };

// round-to-nearest-even f32 -> bf16 bits
__device__ __forceinline__ unsigned bf16r(float f) {
    unsigned u = __float_as_uint(f);
    return ((u + 0x7FFFu + ((u >> 16) & 1u)) >> 16) & 0xFFFFu;
}
#define BF_ONE 0x3F80u

// ---------------------------------------------------------------------------
// MFMA pairwise-d2 kernel. Matrix D[m(ref) rows][n(pred) cols].
// d2 = |r|^2 + |p|^2 - 2 r.p computed entirely inside the MFMA via
// K-slot encoding: A(ref) = [x,y,z,Nh,Nl,1,1,0], B(pred) = [-2x,-2y,-2z,1,1,Nh,Nl,0].
// Norms are split into hi+lo bf16 (reconstruction ~exact); only coordinate
// bf16 rounding remains (~1e-3 on d2 for near-min pairs).
// Per 32x32 tile: 1 ds_read_b128 (B frag), 1 MFMA, 32 VALU (row argmin via
// packed u32 min) + 17 (col min tree). Row mins: in-register across the col
// sweep -> u64 global atomicMin. Col mins: LDS atomicMin -> u32 global atomicMin.
// grid = (M/128, COLSPLIT, B), block = 256.
// ---------------------------------------------------------------------------
__global__ __launch_bounds__(256) void k_pairs(
    const float* __restrict__ pred_pts,   // [B,N,3]
    const float* __restrict__ ref_pts,    // [B,M,3]
    unsigned long long* __restrict__ packed,  // [B*M], init 0xFF
    unsigned int* __restrict__ colminU)       // [B*N], init 0xFF
{
    __shared__ uint4 ldsB[CCHUNK + 1];        // [CCHUNK] is the zero slot
    __shared__ unsigned int ldsCol[CCHUNK];

    const int t    = threadIdx.x;
    const int wave = t >> 6;
    const int lane = t & 63;
    const int l31  = lane & 31;
    const int half = lane >> 5;
    const int rowblk  = blockIdx.x;
    const int colbase = blockIdx.y * CCHUNK;
    const int b       = blockIdx.z;

    // ---- stage pred-point B-vectors into LDS ----
    for (int i = t; i < CCHUNK; i += 256) {
        const float* p = pred_pts + ((size_t)b * N_ + colbase + i) * 3;
        float x = p[0], y = p[1], z = p[2];
        float nrm = x * x + y * y + z * z;
        unsigned nh = bf16r(nrm);
        unsigned nl = bf16r(nrm - __uint_as_float(nh << 16));
        uint4 v;
        v.x = bf16r(-2.f * x) | (bf16r(-2.f * y) << 16);
        v.y = bf16r(-2.f * z) | (BF_ONE << 16);
        v.z = BF_ONE | (nh << 16);
        v.w = nl;                              // slot7 = 0
        ldsB[i] = v;
        ldsCol[i] = 0xFFFFFFFFu;
    }
    if (t == 0) { uint4 z4 = {0, 0, 0, 0}; ldsB[CCHUNK] = z4; }

    // ---- build A frag (ref points), lanes>=32 hold the zero K-half ----
    FragU af; af.u.x = af.u.y = af.u.z = af.u.w = 0;
    const int rowbase = rowblk * ROWS_PER_BLOCK + wave * ROWS_PER_WAVE;
    if (half == 0) {
        const float* r = ref_pts + ((size_t)b * M_ + rowbase + l31) * 3;
        float x = r[0], y = r[1], z = r[2];
        float nrm = x * x + y * y + z * z;
        unsigned nh = bf16r(nrm);
        unsigned nl = bf16r(nrm - __uint_as_float(nh << 16));
        af.u.x = bf16r(x) | (bf16r(y) << 16);
        af.u.y = bf16r(z) | (nh << 16);
        af.u.z = nl | (BF_ONE << 16);
        af.u.w = BF_ONE;                       // slot7 = 0
    }
    __syncthreads();

    f32x16 zero16 = {};
    unsigned rowbest[16];
    #pragma unroll
    for (int i = 0; i < 16; ++i) rowbest[i] = 0xFFFFFFFFu;

    const int bslot = (half == 0) ? l31 : CCHUNK;   // zero slot for hi half
    const int bstep = (half == 0) ? 32 : 0;

    #pragma unroll 2
    for (int tile = 0; tile < NTILES; ++tile) {
        FragU bf_; bf_.u = ldsB[bslot + tile * bstep];
        f32x16 acc = __builtin_amdgcn_mfma_f32_32x32x16_bf16(af.s, bf_.s, zero16, 0, 0, 0);

        // row path: packed (truncated d2 bits | local col), min_u32
        const unsigned lcol = (unsigned)(tile * 32 + l31);
        #pragma unroll
        for (int i = 0; i < 16; ++i) {
            unsigned pk = (__float_as_uint(acc[i]) & 0xFFFFF800u) | lcol;
            rowbest[i] = pk < rowbest[i] ? pk : rowbest[i];
        }
        // col path: min over the 16 rows this lane holds, then fold halves
        float cm = fminf(fminf(fminf(acc[0], acc[1]), fminf(acc[2], acc[3])),
                         fminf(fminf(acc[4], acc[5]), fminf(acc[6], acc[7])));
        float cm2 = fminf(fminf(fminf(acc[8], acc[9]), fminf(acc[10], acc[11])),
                          fminf(fminf(acc[12], acc[13]), fminf(acc[14], acc[15])));
        cm = fminf(cm, cm2);
        cm = fminf(cm, __shfl_xor(cm, 32));
        cm = fmaxf(cm, 0.f);
        if (half == 0)
            atomicMin(&ldsCol[tile * 32 + l31], __float_as_uint(cm));
    }

    // ---- row finalization: reduce across the 32 lanes sharing each row ----
    #pragma unroll
    for (int i = 0; i < 16; ++i) {
        unsigned pk = rowbest[i];
        #pragma unroll
        for (int off = 1; off < 32; off <<= 1) {
            unsigned o = __shfl_xor(pk, off);
            pk = o < pk ? o : pk;
        }
        if (l31 == 0) {
            int row = rowbase + (i & 3) + 8 * (i >> 2) + 4 * half;
            unsigned long long v =
                ((unsigned long long)(pk & 0xFFFFF800u) << 32)
                | (unsigned)(colbase + (pk & 0x7FFu));
            atomicMin(&packed[(size_t)b * M_ + row], v);
        }
    }

    // ---- col finalization ----
    __syncthreads();
    for (int i = t; i < CCHUNK; i += 256)
        atomicMin(&colminU[(size_t)b * N_ + colbase + i], ldsCol[i]);
}

// ---------------------------------------------------------------------------
// Gather + final reduction straight into d_out (pre-zeroed).
// ---------------------------------------------------------------------------
__global__ __launch_bounds__(256) void k_reduce(
    const unsigned long long* __restrict__ packed,  // [B*M]
    const unsigned int* __restrict__ colminU,       // [B*N]
    const float* __restrict__ pred_sdfs,
    const float* __restrict__ pred_cols,
    const float* __restrict__ ref_sdfs,
    const float* __restrict__ ref_cols,
    float* __restrict__ out)   // [3]
{
    const int i = blockIdx.x * 256 + threadIdx.x;   // 0 .. B*M-1
    const int b = i >> 13;

    unsigned long long pk = packed[i];
    float chyx = fmaxf(__uint_as_float((unsigned)(pk >> 32)), 0.f);
    int arg = (int)(unsigned)(pk & 0xFFFFFFFFull);
    float chxy = fmaxf(__uint_as_float(colminU[i]), 0.f);

    float sdf = fabsf(ref_sdfs[(size_t)b * M_ + arg] - pred_sdfs[i]);
    const float* rc = ref_cols + ((size_t)b * M_ + arg) * 3;
    const float* pc = pred_cols + (size_t)i * 3;
    float col = fabsf(rc[0] - pc[0]) + fabsf(rc[1] - pc[1]) + fabsf(rc[2] - pc[2]);

    float cham = chyx * (1.f / (B_ * M_)) + chxy * (1.f / (B_ * N_));
    sdf *= 1.f / (B_ * M_);
    col *= 1.f / (B_ * M_ * 3);

    #pragma unroll
    for (int off = 32; off > 0; off >>= 1) {
        sdf  += __shfl_down(sdf, off);
        col  += __shfl_down(col, off);
        cham += __shfl_down(cham, off);
    }
    if ((threadIdx.x & 63) == 0) {
        atomicAdd(&out[0], sdf);
        atomicAdd(&out[1], col);
        atomicAdd(&out[2], cham);
    }
}

extern "C" void kernel_launch(void* const* d_in, const int* in_sizes, int n_in,
                              void* d_out, int out_size, void* d_ws, size_t ws_size,
                              hipStream_t stream) {
    const float* pred_pts  = (const float*)d_in[0];
    const float* pred_sdfs = (const float*)d_in[1];
    const float* pred_cols = (const float*)d_in[2];
    const float* ref_pts   = (const float*)d_in[3];
    const float* ref_sdfs  = (const float*)d_in[4];
    const float* ref_cols  = (const float*)d_in[5];
    float* out = (float*)d_out;

    char* ws = (char*)d_ws;
    unsigned long long* packed = (unsigned long long*)ws;            // 128 KiB
    unsigned int* colminU = (unsigned int*)(ws + (size_t)B_ * M_ * 8); // 64 KiB

    hipMemsetAsync(ws, 0xFF, (size_t)B_ * M_ * 8 + (size_t)B_ * N_ * 4, stream);
    hipMemsetAsync(out, 0, 3 * sizeof(float), stream);

    dim3 g1(M_ / ROWS_PER_BLOCK, COLSPLIT, B_);   // (64, 4, 2) = 512 blocks
    k_pairs<<<g1, 256, 0, stream>>>(pred_pts, ref_pts, packed, colminU);

    k_reduce<<<(B_ * M_) / 256, 256, 0, stream>>>(
        packed, colminU, pred_sdfs, pred_cols, ref_sdfs, ref_cols, out);
}

// Round 4
// 92.799 us; speedup vs baseline: 1.9292x; 1.1261x over previous
//
#include <hip/hip_runtime.h>
#include <cstdint>
#include <cstddef>

// B=2, N=M=8192, 3-float points.
#define B_ 2
#define N_ 8192
#define M_ 8192
#define COLSPLIT 4
#define CCHUNK (N_ / COLSPLIT)      // 2048 cols per block
#define NTILES (CCHUNK / 32)        // 64 col tiles of 32
#define ROWS_PER_WAVE 32
#define ROWS_PER_BLOCK 128          // 4 waves
#define RBLOCKS ((B_ * M_) / 256)   // 64 reduce blocks

typedef __attribute__((ext_vector_type(8))) short short8;
typedef __attribute__((ext_vector_type(16))) float f32x16;

union FragU { uint4 u; short8 s; };

// round-to-nearest-even f32 -> bf16 bits
__device__ __forceinline__ unsigned bf16r(float f) {
    unsigned u = __float_as_uint(f);
    return ((u + 0x7FFFu + ((u >> 16) & 1u)) >> 16) & 0xFFFFu;
}
#define BF_ONE 0x3F80u

// ---------------------------------------------------------------------------
// Init the atomicMin sentinel arrays (replaces hipMemsetAsync, whose captured
// fillBuffer dispatches cost ~40 us each on this runtime).
// region = packed u64[B*M] + colminU u32[B*N] = 192 KiB = 12288 uint4.
// ---------------------------------------------------------------------------
__global__ __launch_bounds__(256) void k_init(uint4* __restrict__ p)
{
    const int i = blockIdx.x * 256 + threadIdx.x;   // 48 blocks * 256 = 12288
    uint4 v = {0xFFFFFFFFu, 0xFFFFFFFFu, 0xFFFFFFFFu, 0xFFFFFFFFu};
    p[i] = v;
}

// ---------------------------------------------------------------------------
// MFMA pairwise-d2 kernel. Matrix D[m(ref) rows][n(pred) cols].
// d2 = |r|^2 + |p|^2 - 2 r.p computed entirely inside the MFMA via
// K-slot encoding: A(ref) = [x,y,z,Nh,Nl,1,1,0], B(pred) = [-2x,-2y,-2z,1,1,Nh,Nl,0].
// Each 32x32 tile is computed ONCE and feeds BOTH directions (row argmin via
// packed u32 min; col min via in-lane tree + LDS atomicMin).
// grid = (M/128, COLSPLIT, B), block = 256.
// ---------------------------------------------------------------------------
__global__ __launch_bounds__(256) void k_pairs(
    const float* __restrict__ pred_pts,   // [B,N,3]
    const float* __restrict__ ref_pts,    // [B,M,3]
    unsigned long long* __restrict__ packed,  // [B*M], init 0xFF
    unsigned int* __restrict__ colminU)       // [B*N], init 0xFF
{
    __shared__ uint4 ldsB[CCHUNK + 1];        // [CCHUNK] is the zero slot
    __shared__ unsigned int ldsCol[CCHUNK];

    const int t    = threadIdx.x;
    const int wave = t >> 6;
    const int lane = t & 63;
    const int l31  = lane & 31;
    const int half = lane >> 5;
    const int rowblk  = blockIdx.x;
    const int colbase = blockIdx.y * CCHUNK;
    const int b       = blockIdx.z;

    // ---- stage pred-point B-vectors into LDS ----
    for (int i = t; i < CCHUNK; i += 256) {
        const float* p = pred_pts + ((size_t)b * N_ + colbase + i) * 3;
        float x = p[0], y = p[1], z = p[2];
        float nrm = x * x + y * y + z * z;
        unsigned nh = bf16r(nrm);
        unsigned nl = bf16r(nrm - __uint_as_float(nh << 16));
        uint4 v;
        v.x = bf16r(-2.f * x) | (bf16r(-2.f * y) << 16);
        v.y = bf16r(-2.f * z) | (BF_ONE << 16);
        v.z = BF_ONE | (nh << 16);
        v.w = nl;                              // slot7 = 0
        ldsB[i] = v;
        ldsCol[i] = 0xFFFFFFFFu;
    }
    if (t == 0) { uint4 z4 = {0, 0, 0, 0}; ldsB[CCHUNK] = z4; }

    // ---- build A frag (ref points), lanes>=32 hold the zero K-half ----
    FragU af; af.u.x = af.u.y = af.u.z = af.u.w = 0;
    const int rowbase = rowblk * ROWS_PER_BLOCK + wave * ROWS_PER_WAVE;
    if (half == 0) {
        const float* r = ref_pts + ((size_t)b * M_ + rowbase + l31) * 3;
        float x = r[0], y = r[1], z = r[2];
        float nrm = x * x + y * y + z * z;
        unsigned nh = bf16r(nrm);
        unsigned nl = bf16r(nrm - __uint_as_float(nh << 16));
        af.u.x = bf16r(x) | (bf16r(y) << 16);
        af.u.y = bf16r(z) | (nh << 16);
        af.u.z = nl | (BF_ONE << 16);
        af.u.w = BF_ONE;                       // slot7 = 0
    }
    __syncthreads();

    f32x16 zero16 = {};
    unsigned rowbest[16];
    #pragma unroll
    for (int i = 0; i < 16; ++i) rowbest[i] = 0xFFFFFFFFu;

    const int bslot = (half == 0) ? l31 : CCHUNK;   // zero slot for hi half
    const int bstep = (half == 0) ? 32 : 0;

    #pragma unroll 2
    for (int tile = 0; tile < NTILES; ++tile) {
        FragU bf_; bf_.u = ldsB[bslot + tile * bstep];
        f32x16 acc = __builtin_amdgcn_mfma_f32_32x32x16_bf16(af.s, bf_.s, zero16, 0, 0, 0);

        // row path: packed (truncated d2 bits | local col), min_u32
        const unsigned lcol = (unsigned)(tile * 32 + l31);
        #pragma unroll
        for (int i = 0; i < 16; ++i) {
            unsigned pk = (__float_as_uint(acc[i]) & 0xFFFFF800u) | lcol;
            rowbest[i] = pk < rowbest[i] ? pk : rowbest[i];
        }
        // col path: min over the 16 rows this lane holds, then fold halves
        float cm = fminf(fminf(fminf(acc[0], acc[1]), fminf(acc[2], acc[3])),
                         fminf(fminf(acc[4], acc[5]), fminf(acc[6], acc[7])));
        float cm2 = fminf(fminf(fminf(acc[8], acc[9]), fminf(acc[10], acc[11])),
                          fminf(fminf(acc[12], acc[13]), fminf(acc[14], acc[15])));
        cm = fminf(cm, cm2);
        cm = fminf(cm, __shfl_xor(cm, 32));
        cm = fmaxf(cm, 0.f);
        if (half == 0)
            atomicMin(&ldsCol[tile * 32 + l31], __float_as_uint(cm));
    }

    // ---- row finalization: reduce across the 32 lanes sharing each row ----
    #pragma unroll
    for (int i = 0; i < 16; ++i) {
        unsigned pk = rowbest[i];
        #pragma unroll
        for (int off = 1; off < 32; off <<= 1) {
            unsigned o = __shfl_xor(pk, off);
            pk = o < pk ? o : pk;
        }
        if (l31 == 0) {
            int row = rowbase + (i & 3) + 8 * (i >> 2) + 4 * half;
            unsigned long long v =
                ((unsigned long long)(pk & 0xFFFFF800u) << 32)
                | (unsigned)(colbase + (pk & 0x7FFu));
            atomicMin(&packed[(size_t)b * M_ + row], v);
        }
    }

    // ---- col finalization ----
    __syncthreads();
    for (int i = t; i < CCHUNK; i += 256)
        atomicMin(&colminU[(size_t)b * N_ + colbase + i], ldsCol[i]);
}

// ---------------------------------------------------------------------------
// Gather + per-block partial sums (plain stores -> no d_out zeroing needed).
// grid = 64 blocks x 256 threads = B*M threads.
// ---------------------------------------------------------------------------
__global__ __launch_bounds__(256) void k_reduce(
    const unsigned long long* __restrict__ packed,  // [B*M]
    const unsigned int* __restrict__ colminU,       // [B*N]
    const float* __restrict__ pred_sdfs,
    const float* __restrict__ pred_cols,
    const float* __restrict__ ref_sdfs,
    const float* __restrict__ ref_cols,
    float* __restrict__ partials)   // [3][RBLOCKS]
{
    __shared__ float wsum[4][3];
    const int i = blockIdx.x * 256 + threadIdx.x;   // 0 .. B*M-1
    const int b = i >> 13;

    unsigned long long pk = packed[i];
    float chyx = fmaxf(__uint_as_float((unsigned)(pk >> 32)), 0.f);
    int arg = (int)(unsigned)(pk & 0xFFFFFFFFull);
    float chxy = fmaxf(__uint_as_float(colminU[i]), 0.f);

    float sdf = fabsf(ref_sdfs[(size_t)b * M_ + arg] - pred_sdfs[i]);
    const float* rc = ref_cols + ((size_t)b * M_ + arg) * 3;
    const float* pc = pred_cols + (size_t)i * 3;
    float col = fabsf(rc[0] - pc[0]) + fabsf(rc[1] - pc[1]) + fabsf(rc[2] - pc[2]);

    float cham = chyx * (1.f / (B_ * M_)) + chxy * (1.f / (B_ * N_));
    sdf *= 1.f / (B_ * M_);
    col *= 1.f / (B_ * M_ * 3);

    #pragma unroll
    for (int off = 32; off > 0; off >>= 1) {
        sdf  += __shfl_down(sdf, off);
        col  += __shfl_down(col, off);
        cham += __shfl_down(cham, off);
    }
    const int wave = threadIdx.x >> 6;
    if ((threadIdx.x & 63) == 0) {
        wsum[wave][0] = sdf; wsum[wave][1] = col; wsum[wave][2] = cham;
    }
    __syncthreads();
    if (threadIdx.x == 0) {
        partials[0 * RBLOCKS + blockIdx.x] = wsum[0][0] + wsum[1][0] + wsum[2][0] + wsum[3][0];
        partials[1 * RBLOCKS + blockIdx.x] = wsum[0][1] + wsum[1][1] + wsum[2][1] + wsum[3][1];
        partials[2 * RBLOCKS + blockIdx.x] = wsum[0][2] + wsum[1][2] + wsum[2][2] + wsum[3][2];
    }
}

// ---------------------------------------------------------------------------
// Sum the 64 partials per output and plain-store d_out (overwrites poison).
// ---------------------------------------------------------------------------
__global__ void k_final(const float* __restrict__ partials, float* __restrict__ out)
{
    const int t = threadIdx.x;    // 64 threads
    float s0 = partials[0 * RBLOCKS + t];
    float s1 = partials[1 * RBLOCKS + t];
    float s2 = partials[2 * RBLOCKS + t];
    #pragma unroll
    for (int off = 32; off > 0; off >>= 1) {
        s0 += __shfl_down(s0, off);
        s1 += __shfl_down(s1, off);
        s2 += __shfl_down(s2, off);
    }
    if (t == 0) { out[0] = s0; out[1] = s1; out[2] = s2; }
}

extern "C" void kernel_launch(void* const* d_in, const int* in_sizes, int n_in,
                              void* d_out, int out_size, void* d_ws, size_t ws_size,
                              hipStream_t stream) {
    const float* pred_pts  = (const float*)d_in[0];
    const float* pred_sdfs = (const float*)d_in[1];
    const float* pred_cols = (const float*)d_in[2];
    const float* ref_pts   = (const float*)d_in[3];
    const float* ref_sdfs  = (const float*)d_in[4];
    const float* ref_cols  = (const float*)d_in[5];
    float* out = (float*)d_out;

    // ws layout: [packed u64 B*M =128KiB][colminU u32 B*N =64KiB][partials 3*64 f32]
    char* ws = (char*)d_ws;
    unsigned long long* packed = (unsigned long long*)ws;
    unsigned int* colminU = (unsigned int*)(ws + (size_t)B_ * M_ * 8);
    float* partials = (float*)(ws + (size_t)B_ * M_ * 8 + (size_t)B_ * N_ * 4);

    // 192 KiB sentinel init = 12288 uint4 stores across 48 blocks.
    k_init<<<48, 256, 0, stream>>>((uint4*)ws);

    dim3 g1(M_ / ROWS_PER_BLOCK, COLSPLIT, B_);   // (64, 4, 2) = 512 blocks
    k_pairs<<<g1, 256, 0, stream>>>(pred_pts, ref_pts, packed, colminU);

    k_reduce<<<RBLOCKS, 256, 0, stream>>>(
        packed, colminU, pred_sdfs, pred_cols, ref_sdfs, ref_cols, partials);

    k_final<<<1, 64, 0, stream>>>(partials, out);
}

// Round 5
// 90.265 us; speedup vs baseline: 1.9834x; 1.0281x over previous
//
#include <hip/hip_runtime.h>
#include <cstdint>
#include <cstddef>

// B=2, N=M=8192, 3-float points.
#define B_ 2
#define N_ 8192
#define M_ 8192
#define COLSPLIT 8
#define CCHUNK (N_ / COLSPLIT)      // 1024 cols per block
#define NTILES (CCHUNK / 32)        // 32 col tiles of 32
#define ROWS_PER_WAVE 32
#define ROWS_PER_BLOCK 128          // 4 waves
#define RBLOCKS ((B_ * M_) / 256)   // 64 reduce blocks

typedef __attribute__((ext_vector_type(8))) short short8;
typedef __attribute__((ext_vector_type(16))) float f32x16;

union FragU { uint4 u; short8 s; };

// round-to-nearest-even f32 -> bf16 bits
__device__ __forceinline__ unsigned bf16r(float f) {
    unsigned u = __float_as_uint(f);
    return ((u + 0x7FFFu + ((u >> 16) & 1u)) >> 16) & 0xFFFFu;
}
#define BF_ONE 0x3F80u

__device__ __forceinline__ unsigned umin_(unsigned a, unsigned b) { return a < b ? a : b; }

// ---------------------------------------------------------------------------
// Sentinel init for the atomicMin arrays (192 KiB = 12288 uint4).
// ---------------------------------------------------------------------------
__global__ __launch_bounds__(256) void k_init(uint4* __restrict__ p)
{
    const int i = blockIdx.x * 256 + threadIdx.x;   // 48 * 256 = 12288
    uint4 v = {0xFFFFFFFFu, 0xFFFFFFFFu, 0xFFFFFFFFu, 0xFFFFFFFFu};
    p[i] = v;
}

// ---------------------------------------------------------------------------
// MFMA pairwise-d2 kernel. D[m(ref) rows][n(pred) cols], both directions from
// one tile sweep. K-slot encoding puts |r|^2+|p|^2-2r.p inside the MFMA:
// A(ref)=[x,y,z,Nh,Nl,1,1,0], B(pred)=[-2x,-2y,-2z,1,1,Nh,Nl,0].
// 2 tiles per iteration (2 MFMAs in flight); row argmin via v_and_or_b32 pack
// + v_min3_u32; col min via in-lane fmin tree + LDS atomicMin from BOTH
// 32-lane halves (no per-tile shuffle in the dependent chain).
// grid = (M/128, COLSPLIT, B) = (64, 8, 2) = 1024 blocks, 4 waves/SIMD.
// ---------------------------------------------------------------------------
__global__ __launch_bounds__(256, 4) void k_pairs(
    const float* __restrict__ pred_pts,   // [B,N,3]
    const float* __restrict__ ref_pts,    // [B,M,3]
    unsigned long long* __restrict__ packed,  // [B*M], init 0xFF
    unsigned int* __restrict__ colminU)       // [B*N], init 0xFF
{
    __shared__ uint4 ldsB[CCHUNK + 1];        // [CCHUNK] is the zero slot
    __shared__ unsigned int ldsCol[CCHUNK];

    const int t    = threadIdx.x;
    const int wave = t >> 6;
    const int lane = t & 63;
    const int l31  = lane & 31;
    const int half = lane >> 5;
    const int rowblk  = blockIdx.x;
    const int colbase = blockIdx.y * CCHUNK;
    const int b       = blockIdx.z;

    // ---- stage pred-point B-vectors into LDS ----
    for (int i = t; i < CCHUNK; i += 256) {
        const float* p = pred_pts + ((size_t)b * N_ + colbase + i) * 3;
        float x = p[0], y = p[1], z = p[2];
        float nrm = x * x + y * y + z * z;
        unsigned nh = bf16r(nrm);
        unsigned nl = bf16r(nrm - __uint_as_float(nh << 16));
        uint4 v;
        v.x = bf16r(-2.f * x) | (bf16r(-2.f * y) << 16);
        v.y = bf16r(-2.f * z) | (BF_ONE << 16);
        v.z = BF_ONE | (nh << 16);
        v.w = nl;                              // slot7 = 0
        ldsB[i] = v;
        ldsCol[i] = 0xFFFFFFFFu;
    }
    if (t == 0) { uint4 z4 = {0, 0, 0, 0}; ldsB[CCHUNK] = z4; }

    // ---- A frag (ref points); lanes >= 32 hold the zero K-half ----
    FragU af; af.u.x = af.u.y = af.u.z = af.u.w = 0;
    const int rowbase = rowblk * ROWS_PER_BLOCK + wave * ROWS_PER_WAVE;
    if (half == 0) {
        const float* r = ref_pts + ((size_t)b * M_ + rowbase + l31) * 3;
        float x = r[0], y = r[1], z = r[2];
        float nrm = x * x + y * y + z * z;
        unsigned nh = bf16r(nrm);
        unsigned nl = bf16r(nrm - __uint_as_float(nh << 16));
        af.u.x = bf16r(x) | (bf16r(y) << 16);
        af.u.y = bf16r(z) | (nh << 16);
        af.u.z = nl | (BF_ONE << 16);
        af.u.w = BF_ONE;                       // slot7 = 0
    }
    __syncthreads();

    f32x16 zero16 = {};
    unsigned rowbest[16];
    #pragma unroll
    for (int i = 0; i < 16; ++i) rowbest[i] = 0xFFFFFFFFu;

    const int bslot = (half == 0) ? l31 : CCHUNK;   // zero slot for hi half
    const int bstep = (half == 0) ? 32 : 0;

    #pragma unroll 2
    for (int tile = 0; tile < NTILES; tile += 2) {
        FragU b0; b0.u = ldsB[bslot + tile * bstep];
        FragU b1; b1.u = ldsB[bslot + (tile + 1) * bstep];
        f32x16 acc0 = __builtin_amdgcn_mfma_f32_32x32x16_bf16(af.s, b0.s, zero16, 0, 0, 0);
        f32x16 acc1 = __builtin_amdgcn_mfma_f32_32x32x16_bf16(af.s, b1.s, zero16, 0, 0, 0);

        const unsigned lcol0 = (unsigned)(tile * 32 + l31);
        const unsigned lcol1 = lcol0 + 32;
        #pragma unroll
        for (int i = 0; i < 16; ++i) {
            unsigned pk0 = (__float_as_uint(acc0[i]) & 0xFFFFF800u) | lcol0;  // v_and_or_b32
            unsigned pk1 = (__float_as_uint(acc1[i]) & 0xFFFFF800u) | lcol1;
            rowbest[i] = umin_(rowbest[i], umin_(pk0, pk1));                  // v_min3_u32
        }
        // col path: fmin tree over this lane's 16 rows, both halves atomicMin
        float c0 = fminf(fminf(fminf(fminf(acc0[0], acc0[1]), fminf(acc0[2], acc0[3])),
                               fminf(fminf(acc0[4], acc0[5]), fminf(acc0[6], acc0[7]))),
                         fminf(fminf(fminf(acc0[8], acc0[9]), fminf(acc0[10], acc0[11])),
                               fminf(fminf(acc0[12], acc0[13]), fminf(acc0[14], acc0[15]))));
        float c1 = fminf(fminf(fminf(fminf(acc1[0], acc1[1]), fminf(acc1[2], acc1[3])),
                               fminf(fminf(acc1[4], acc1[5]), fminf(acc1[6], acc1[7]))),
                         fminf(fminf(fminf(acc1[8], acc1[9]), fminf(acc1[10], acc1[11])),
                               fminf(fminf(acc1[12], acc1[13]), fminf(acc1[14], acc1[15]))));
        atomicMin(&ldsCol[lcol0], __float_as_uint(c0));
        atomicMin(&ldsCol[lcol1], __float_as_uint(c1));
    }

    // ---- row finalization: min across the 32 lanes sharing each row ----
    #pragma unroll
    for (int i = 0; i < 16; ++i) {
        unsigned pk = rowbest[i];
        #pragma unroll
        for (int off = 1; off < 32; off <<= 1) {
            unsigned o = __shfl_xor(pk, off);
            pk = o < pk ? o : pk;
        }
        if (l31 == 0) {
            int row = rowbase + (i & 3) + 8 * (i >> 2) + 4 * half;
            unsigned long long v =
                ((unsigned long long)(pk & 0xFFFFF800u) << 32)
                | (unsigned)(colbase + (pk & 0x7FFu));
            atomicMin(&packed[(size_t)b * M_ + row], v);
        }
    }

    // ---- col finalization ----
    __syncthreads();
    for (int i = t; i < CCHUNK; i += 256)
        atomicMin(&colminU[(size_t)b * N_ + colbase + i], ldsCol[i]);
}

// ---------------------------------------------------------------------------
// Gather + per-block partials (plain stores; no d_out zeroing needed).
// ---------------------------------------------------------------------------
__global__ __launch_bounds__(256) void k_reduce(
    const unsigned long long* __restrict__ packed,  // [B*M]
    const unsigned int* __restrict__ colminU,       // [B*N]
    const float* __restrict__ pred_sdfs,
    const float* __restrict__ pred_cols,
    const float* __restrict__ ref_sdfs,
    const float* __restrict__ ref_cols,
    float* __restrict__ partials)   // [3][RBLOCKS]
{
    __shared__ float wsum[4][3];
    const int i = blockIdx.x * 256 + threadIdx.x;   // 0 .. B*M-1
    const int b = i >> 13;

    unsigned long long pk = packed[i];
    float chyx = fmaxf(__uint_as_float((unsigned)(pk >> 32)), 0.f);
    int arg = (int)(unsigned)(pk & 0xFFFFFFFFull);
    float chxy = fmaxf(__uint_as_float(colminU[i]), 0.f);

    float sdf = fabsf(ref_sdfs[(size_t)b * M_ + arg] - pred_sdfs[i]);
    const float* rc = ref_cols + ((size_t)b * M_ + arg) * 3;
    const float* pc = pred_cols + (size_t)i * 3;
    float col = fabsf(rc[0] - pc[0]) + fabsf(rc[1] - pc[1]) + fabsf(rc[2] - pc[2]);

    float cham = chyx * (1.f / (B_ * M_)) + chxy * (1.f / (B_ * N_));
    sdf *= 1.f / (B_ * M_);
    col *= 1.f / (B_ * M_ * 3);

    #pragma unroll
    for (int off = 32; off > 0; off >>= 1) {
        sdf  += __shfl_down(sdf, off);
        col  += __shfl_down(col, off);
        cham += __shfl_down(cham, off);
    }
    const int wave = threadIdx.x >> 6;
    if ((threadIdx.x & 63) == 0) {
        wsum[wave][0] = sdf; wsum[wave][1] = col; wsum[wave][2] = cham;
    }
    __syncthreads();
    if (threadIdx.x == 0) {
        partials[0 * RBLOCKS + blockIdx.x] = wsum[0][0] + wsum[1][0] + wsum[2][0] + wsum[3][0];
        partials[1 * RBLOCKS + blockIdx.x] = wsum[0][1] + wsum[1][1] + wsum[2][1] + wsum[3][1];
        partials[2 * RBLOCKS + blockIdx.x] = wsum[0][2] + wsum[1][2] + wsum[2][2] + wsum[3][2];
    }
}

__global__ void k_final(const float* __restrict__ partials, float* __restrict__ out)
{
    const int t = threadIdx.x;    // 64 threads
    float s0 = partials[0 * RBLOCKS + t];
    float s1 = partials[1 * RBLOCKS + t];
    float s2 = partials[2 * RBLOCKS + t];
    #pragma unroll
    for (int off = 32; off > 0; off >>= 1) {
        s0 += __shfl_down(s0, off);
        s1 += __shfl_down(s1, off);
        s2 += __shfl_down(s2, off);
    }
    if (t == 0) { out[0] = s0; out[1] = s1; out[2] = s2; }
}

extern "C" void kernel_launch(void* const* d_in, const int* in_sizes, int n_in,
                              void* d_out, int out_size, void* d_ws, size_t ws_size,
                              hipStream_t stream) {
    const float* pred_pts  = (const float*)d_in[0];
    const float* pred_sdfs = (const float*)d_in[1];
    const float* pred_cols = (const float*)d_in[2];
    const float* ref_pts   = (const float*)d_in[3];
    const float* ref_sdfs  = (const float*)d_in[4];
    const float* ref_cols  = (const float*)d_in[5];
    float* out = (float*)d_out;

    // ws layout: [packed u64 B*M =128KiB][colminU u32 B*N =64KiB][partials 3*64 f32]
    char* ws = (char*)d_ws;
    unsigned long long* packed = (unsigned long long*)ws;
    unsigned int* colminU = (unsigned int*)(ws + (size_t)B_ * M_ * 8);
    float* partials = (float*)(ws + (size_t)B_ * M_ * 8 + (size_t)B_ * N_ * 4);

    k_init<<<48, 256, 0, stream>>>((uint4*)ws);

    dim3 g1(M_ / ROWS_PER_BLOCK, COLSPLIT, B_);   // (64, 8, 2) = 1024 blocks
    k_pairs<<<g1, 256, 0, stream>>>(pred_pts, ref_pts, packed, colminU);

    k_reduce<<<RBLOCKS, 256, 0, stream>>>(
        packed, colminU, pred_sdfs, pred_cols, ref_sdfs, ref_cols, partials);

    k_final<<<1, 64, 0, stream>>>(partials, out);
}